// Round 1
// baseline (833.049 us; speedup 1.0000x reference)
//
#include <hip/hip_runtime.h>

// ---------------------------------------------------------------------------
// Llama4TextExperts: per-expert  out = (up * silu(gate)) @ W2
//   gate_up = x_e @ W1_e   (W1: (H, 2I)), gate = [:, :I], up = [:, I:]
// Shapes: E=8, T=8192 (1024/expert), H=2048, I=4096. fp32 in/out.
// Strategy: bf16 MFMA (tolerance allows bf16): convert+transpose weights to
// (N,K) bf16 in ws, then two m97-style 128x128 MFMA GEMMs, SiLU fused into
// GEMM1 epilogue (gate tile + up tile computed by the same block).
// ---------------------------------------------------------------------------

#define E_   8
#define H_   2048
#define I_   4096
#define T_   8192
#define TPE  1024   // tokens per expert

typedef __bf16 bf16x8 __attribute__((ext_vector_type(8)));
typedef float  f32x4  __attribute__((ext_vector_type(4)));

__device__ __forceinline__ unsigned short f2bf(float f) {
  union { float f; unsigned int u; } v; v.f = f;
  unsigned int u = v.u;
  u += 0x7FFFu + ((u >> 16) & 1u);   // round-to-nearest-even
  return (unsigned short)(u >> 16);
}

// async global->LDS, 16B per lane. LDS dest must be wave-uniform base;
// HW writes base + lane*16.
__device__ __forceinline__ void async16(const void* g, void* l) {
  __builtin_amdgcn_global_load_lds(
      (__attribute__((address_space(1))) void*)(g),
      (__attribute__((address_space(3))) void*)(l), 16, 0, 0);
}

// ---------------------------------------------------------------------------
// fp32 -> bf16 elementwise convert (vectorized float4 -> ushort4)
// ---------------------------------------------------------------------------
__global__ void convert_bf16(const float* __restrict__ src,
                             unsigned short* __restrict__ dst, long n) {
  long i = ((long)blockIdx.x * blockDim.x + threadIdx.x) * 4;
  const long stride = (long)gridDim.x * blockDim.x * 4;
  for (; i < n; i += stride) {
    const float4 v = *(const float4*)&src[i];
    ushort4 o;
    o.x = f2bf(v.x); o.y = f2bf(v.y); o.z = f2bf(v.z); o.w = f2bf(v.w);
    *(ushort4*)&dst[i] = o;
  }
}

// ---------------------------------------------------------------------------
// (K,N) fp32 -> (N,K) bf16 tiled transpose. grid: (N/32, K/32, E)
// ---------------------------------------------------------------------------
__global__ void transpose_bf16(const float* __restrict__ src,
                               unsigned short* __restrict__ dst,
                               int K, int N) {
  __shared__ float tile[32][33];
  const long base = (long)blockIdx.z * (long)K * (long)N;
  src += base; dst += base;
  const int n0 = blockIdx.x * 32, k0 = blockIdx.y * 32;
  const int r  = threadIdx.x >> 3;        // 0..31
  const int c4 = (threadIdx.x & 7) * 4;   // 0..28

  const float4 v = *(const float4*)&src[(long)(k0 + r) * N + n0 + c4];
  tile[r][c4 + 0] = v.x; tile[r][c4 + 1] = v.y;
  tile[r][c4 + 2] = v.z; tile[r][c4 + 3] = v.w;
  __syncthreads();

  ushort4 o;  // dst(n0+r, k0+c4+i) = src(k0+c4+i, n0+r) = tile[c4+i][r]
  o.x = f2bf(tile[c4 + 0][r]);
  o.y = f2bf(tile[c4 + 1][r]);
  o.z = f2bf(tile[c4 + 2][r]);
  o.w = f2bf(tile[c4 + 3][r]);
  *(ushort4*)&dst[(long)(n0 + r) * K + k0 + c4] = o;
}

// ---------------------------------------------------------------------------
// GEMM1 + SiLU: A (TPE x H) bf16 row-major, Bt = W1^T (2I x H) bf16 row-major.
// Block computes 128x128 gate tile (cols n0..) AND 128x128 up tile
// (cols I_+n0..) sharing the A tile. Epilogue: acted = up * silu(gate), bf16.
// grid: (TPE/128, I_/128, E). block 256 = 4 waves (2x2), wave tile 64x64 x2.
// ---------------------------------------------------------------------------
__global__ __launch_bounds__(256, 2)
void gemm1_silu(const unsigned short* __restrict__ A,
                const unsigned short* __restrict__ Bt,
                unsigned short* __restrict__ Cact,
                long sA, long sB, long sC) {
  __shared__ unsigned short As [128 * 32];
  __shared__ unsigned short Bgs[128 * 32];
  __shared__ unsigned short Bus[128 * 32];

  const int tid  = threadIdx.x;
  const int wave = tid >> 6;
  const int lane = tid & 63;

  A    += (long)blockIdx.z * sA;
  Bt   += (long)blockIdx.z * sB;
  Cact += (long)blockIdx.z * sC;

  const int m0 = blockIdx.x * 128;
  const int n0 = blockIdx.y * 128;
  const int wr = wave >> 1;
  const int wc = wave & 1;

  f32x4 accg[4][4], accu[4][4];
#pragma unroll
  for (int m = 0; m < 4; ++m)
#pragma unroll
    for (int n = 0; n < 4; ++n) { accg[m][n] = 0.0f; accu[m][n] = 0.0f; }

  const int sr = tid >> 2;          // staging row 0..63 (per half)
  const int sc = (tid & 3) * 8;     // staging k-col

#pragma unroll 1
  for (int k0 = 0; k0 < H_; k0 += 32) {
    __syncthreads();
#pragma unroll
    for (int i = 0; i < 2; ++i) {
      const int r = i * 64 + sr;
      async16(A  + (long)(m0 + r) * H_ + k0 + sc,        &As [(i * 64 + wave * 16) * 32]);
      async16(Bt + (long)(n0 + r) * H_ + k0 + sc,        &Bgs[(i * 64 + wave * 16) * 32]);
      async16(Bt + (long)(I_ + n0 + r) * H_ + k0 + sc,   &Bus[(i * 64 + wave * 16) * 32]);
    }
    __syncthreads();

    bf16x8 af[4], bg[4], bu[4];
    const int lr = lane & 15;
    const int lk = (lane >> 4) * 8;
#pragma unroll
    for (int m = 0; m < 4; ++m)
      af[m] = *(const bf16x8*)&As[(wr * 64 + m * 16 + lr) * 32 + lk];
#pragma unroll
    for (int n = 0; n < 4; ++n) {
      bg[n] = *(const bf16x8*)&Bgs[(wc * 64 + n * 16 + lr) * 32 + lk];
      bu[n] = *(const bf16x8*)&Bus[(wc * 64 + n * 16 + lr) * 32 + lk];
    }
#pragma unroll
    for (int m = 0; m < 4; ++m)
#pragma unroll
      for (int n = 0; n < 4; ++n) {
        accg[m][n] = __builtin_amdgcn_mfma_f32_16x16x32_bf16(af[m], bg[n], accg[m][n], 0, 0, 0);
        accu[m][n] = __builtin_amdgcn_mfma_f32_16x16x32_bf16(af[m], bu[n], accu[m][n], 0, 0, 0);
      }
  }

  // epilogue: C/D layout col=lane&15, row=(lane>>4)*4+r  [m89-verified]
  const int lr = lane & 15;
  const int lq = lane >> 4;
#pragma unroll
  for (int m = 0; m < 4; ++m)
#pragma unroll
    for (int n = 0; n < 4; ++n)
#pragma unroll
      for (int r = 0; r < 4; ++r) {
        const int row = m0 + wr * 64 + m * 16 + lq * 4 + r;
        const int col = n0 + wc * 64 + n * 16 + lr;
        const float g = accg[m][n][r];
        const float u = accu[m][n][r];
        const float s = u * (g / (1.0f + __expf(-g)));   // up * silu(gate)
        Cact[(long)row * I_ + col] = f2bf(s);
      }
}

// ---------------------------------------------------------------------------
// GEMM2: A = acted (TPE x I) bf16, Bt = W2^T (H x I) bf16, C fp32 (TPE x H).
// grid: (TPE/128, H_/128, E). block 256 = 4 waves (2x2), wave tile 64x64.
// ---------------------------------------------------------------------------
__global__ __launch_bounds__(256, 2)
void gemm2_k(const unsigned short* __restrict__ A,
             const unsigned short* __restrict__ Bt,
             float* __restrict__ C,
             long sA, long sB, long sC) {
  __shared__ unsigned short As[128 * 32];
  __shared__ unsigned short Bs[128 * 32];

  const int tid  = threadIdx.x;
  const int wave = tid >> 6;
  const int lane = tid & 63;

  A  += (long)blockIdx.z * sA;
  Bt += (long)blockIdx.z * sB;
  C  += (long)blockIdx.z * sC;

  const int m0 = blockIdx.x * 128;
  const int n0 = blockIdx.y * 128;
  const int wr = wave >> 1;
  const int wc = wave & 1;

  f32x4 acc[4][4];
#pragma unroll
  for (int m = 0; m < 4; ++m)
#pragma unroll
    for (int n = 0; n < 4; ++n) acc[m][n] = 0.0f;

  const int sr = tid >> 2;
  const int sc = (tid & 3) * 8;

#pragma unroll 1
  for (int k0 = 0; k0 < I_; k0 += 32) {
    __syncthreads();
#pragma unroll
    for (int i = 0; i < 2; ++i) {
      const int r = i * 64 + sr;
      async16(A  + (long)(m0 + r) * I_ + k0 + sc, &As[(i * 64 + wave * 16) * 32]);
      async16(Bt + (long)(n0 + r) * I_ + k0 + sc, &Bs[(i * 64 + wave * 16) * 32]);
    }
    __syncthreads();

    bf16x8 af[4], bf[4];
    const int lr = lane & 15;
    const int lk = (lane >> 4) * 8;
#pragma unroll
    for (int m = 0; m < 4; ++m)
      af[m] = *(const bf16x8*)&As[(wr * 64 + m * 16 + lr) * 32 + lk];
#pragma unroll
    for (int n = 0; n < 4; ++n)
      bf[n] = *(const bf16x8*)&Bs[(wc * 64 + n * 16 + lr) * 32 + lk];
#pragma unroll
    for (int m = 0; m < 4; ++m)
#pragma unroll
      for (int n = 0; n < 4; ++n)
        acc[m][n] = __builtin_amdgcn_mfma_f32_16x16x32_bf16(af[m], bf[n], acc[m][n], 0, 0, 0);
  }

  const int lr = lane & 15;
  const int lq = lane >> 4;
#pragma unroll
  for (int m = 0; m < 4; ++m)
#pragma unroll
    for (int n = 0; n < 4; ++n)
#pragma unroll
      for (int r = 0; r < 4; ++r) {
        const int row = m0 + wr * 64 + m * 16 + lq * 4 + r;
        const int col = n0 + wc * 64 + n * 16 + lr;
        C[(long)row * H_ + col] = acc[m][n][r];
      }
}

// ---------------------------------------------------------------------------
extern "C" void kernel_launch(void* const* d_in, const int* in_sizes, int n_in,
                              void* d_out, int out_size, void* d_ws, size_t ws_size,
                              hipStream_t stream) {
  const float* hs = (const float*)d_in[0];   // (8192, 2048)
  const float* w1 = (const float*)d_in[1];   // (8, 2048, 8192)
  const float* w2 = (const float*)d_in[2];   // (8, 4096, 2048)
  float* out = (float*)d_out;                // (8192, 2048) fp32
  char* ws = (char*)d_ws;

  const long HB_B   = (long)T_ * H_ * 2;              //  32 MiB hidden bf16
  const long ACT_B  = (long)T_ * I_ * 2;              //  64 MiB acted bf16
  const long W1T_B  = (long)E_ * 2 * I_ * H_ * 2;     // 256 MiB W1^T bf16
  const long W2T_B  = (long)E_ * H_ * I_ * 2;         // 128 MiB W2^T bf16
  const size_t needFull = (size_t)(HB_B + ACT_B + W1T_B + W2T_B);   // 480 MiB

  if (ws_size >= needFull) {
    unsigned short* hiddenB = (unsigned short*)(ws);
    unsigned short* acted   = (unsigned short*)(ws + HB_B);
    unsigned short* W1t     = (unsigned short*)(ws + HB_B + ACT_B);
    unsigned short* W2t     = (unsigned short*)(ws + HB_B + ACT_B + W1T_B);

    hipLaunchKernelGGL(convert_bf16, dim3(2048), dim3(256), 0, stream,
                       hs, hiddenB, (long)T_ * H_);
    hipLaunchKernelGGL(transpose_bf16, dim3((2 * I_) / 32, H_ / 32, E_), dim3(256), 0, stream,
                       w1, W1t, H_, 2 * I_);
    hipLaunchKernelGGL(transpose_bf16, dim3(H_ / 32, I_ / 32, E_), dim3(256), 0, stream,
                       w2, W2t, I_, H_);
    hipLaunchKernelGGL(gemm1_silu, dim3(TPE / 128, I_ / 128, E_), dim3(256), 0, stream,
                       hiddenB, W1t, acted,
                       (long)TPE * H_, (long)2 * I_ * H_, (long)TPE * I_);
    hipLaunchKernelGGL(gemm2_k, dim3(TPE / 128, H_ / 128, E_), dim3(256), 0, stream,
                       acted, W2t, out,
                       (long)TPE * I_, (long)H_ * I_, (long)TPE * H_);
    return;
  }

  // --- sequential per-expert fallback: needs only ~60 MiB of ws -----------
  const long hbE  = (long)TPE * H_ * 2;        //  4 MiB
  const long actE = (long)TPE * I_ * 2;        //  8 MiB
  const long w1E  = (long)2 * I_ * H_ * 2;     // 32 MiB
  const long w2E  = (long)H_ * I_ * 2;         // 16 MiB
  const size_t needSeq = (size_t)(hbE + actE + w1E + w2E);
  if (ws_size < needSeq) return;               // cannot run safely

  unsigned short* hiddenB = (unsigned short*)(ws);
  unsigned short* acted   = (unsigned short*)(ws + hbE);
  unsigned short* W1t     = (unsigned short*)(ws + hbE + actE);
  unsigned short* W2t     = (unsigned short*)(ws + hbE + actE + w1E);

  for (int e = 0; e < E_; ++e) {
    hipLaunchKernelGGL(convert_bf16, dim3(512), dim3(256), 0, stream,
                       hs + (long)e * TPE * H_, hiddenB, (long)TPE * H_);
    hipLaunchKernelGGL(transpose_bf16, dim3((2 * I_) / 32, H_ / 32, 1), dim3(256), 0, stream,
                       w1 + (long)e * H_ * 2 * I_, W1t, H_, 2 * I_);
    hipLaunchKernelGGL(gemm1_silu, dim3(TPE / 128, I_ / 128, 1), dim3(256), 0, stream,
                       hiddenB, W1t, acted, 0, 0, 0);
    hipLaunchKernelGGL(transpose_bf16, dim3(H_ / 32, I_ / 32, 1), dim3(256), 0, stream,
                       w2 + (long)e * I_ * H_, W2t, I_, H_);
    hipLaunchKernelGGL(gemm2_k, dim3(TPE / 128, H_ / 128, 1), dim3(256), 0, stream,
                       acted, W2t, out + (long)e * TPE * H_, 0, 0, 0);
  }
}

// Round 2
// 620.229 us; speedup vs baseline: 1.3431x; 1.3431x over previous
//
#include <hip/hip_runtime.h>

// ---------------------------------------------------------------------------
// Llama4TextExperts: per-expert  out = (up * silu(gate)) @ W2
// E=8, T=8192 (1024/expert), H=2048, I=4096, fp32 in/out, bf16 compute.
// R2: 256x256x64 8-phase counted-vmcnt GEMM template (T1+T2+T3+T4+T5),
//     gate/up interleaved in W1^T prepass so SiLU fuses in-register.
// ---------------------------------------------------------------------------

#define E_   8
#define H_   2048
#define I_   4096
#define T_   8192
#define TPE  1024

typedef __bf16 bf16x8 __attribute__((ext_vector_type(8)));
typedef float  f32x4  __attribute__((ext_vector_type(4)));

__device__ __forceinline__ unsigned short f2bf(float f) {
  union { float f; unsigned int u; } v; v.f = f;
  unsigned int u = v.u;
  u += 0x7FFFu + ((u >> 16) & 1u);   // RNE
  return (unsigned short)(u >> 16);
}

__device__ __forceinline__ void async16(const void* g, void* l) {
  __builtin_amdgcn_global_load_lds(
      (__attribute__((address_space(1))) void*)(g),
      (__attribute__((address_space(3))) void*)(l), 16, 0, 0);
}

// ---------------------------------------------------------------------------
__global__ void convert_bf16(const float* __restrict__ src,
                             unsigned short* __restrict__ dst, long n) {
  long i = ((long)blockIdx.x * blockDim.x + threadIdx.x) * 4;
  const long stride = (long)gridDim.x * blockDim.x * 4;
  for (; i < n; i += stride) {
    const float4 v = *(const float4*)&src[i];
    ushort4 o;
    o.x = f2bf(v.x); o.y = f2bf(v.y); o.z = f2bf(v.z); o.w = f2bf(v.w);
    *(ushort4*)&dst[i] = o;
  }
}

// (K,N) fp32 -> (N,K) bf16 plain transpose (used for W2). grid (N/32,K/32,E)
__global__ void transpose_bf16(const float* __restrict__ src,
                               unsigned short* __restrict__ dst,
                               int K, int N) {
  __shared__ float tile[32][33];
  const long base = (long)blockIdx.z * (long)K * (long)N;
  src += base; dst += base;
  const int n0 = blockIdx.x * 32, k0 = blockIdx.y * 32;
  const int r  = threadIdx.x >> 3;
  const int c4 = (threadIdx.x & 7) * 4;

  const float4 v = *(const float4*)&src[(long)(k0 + r) * N + n0 + c4];
  tile[r][c4 + 0] = v.x; tile[r][c4 + 1] = v.y;
  tile[r][c4 + 2] = v.z; tile[r][c4 + 3] = v.w;
  __syncthreads();

  ushort4 o;
  o.x = f2bf(tile[c4 + 0][r]);
  o.y = f2bf(tile[c4 + 1][r]);
  o.z = f2bf(tile[c4 + 2][r]);
  o.w = f2bf(tile[c4 + 3][r]);
  *(ushort4*)&dst[(long)(n0 + r) * K + k0 + c4] = o;
}

// W1 (H, 2I) fp32 -> permuted W1^T (2I, H) bf16: dest row interleaves
// gate/up at period 32 (16 gate cols c..c+15, then up for same cols), so
// a 256-row B-tile carries matching gate/up pairs in alternating n-frags.
__global__ void transpose_w1_perm(const float* __restrict__ src,
                                  unsigned short* __restrict__ dst) {
  __shared__ float tile[32][33];
  const long sbase = (long)blockIdx.z * (long)H_ * (2 * I_);
  const long dbase = (long)blockIdx.z * (long)(2 * I_) * H_;
  const int n0 = blockIdx.x * 32, k0 = blockIdx.y * 32;
  const int r  = threadIdx.x >> 3;
  const int c4 = (threadIdx.x & 7) * 4;

  const float4 v = *(const float4*)&src[sbase + (long)(k0 + r) * (2 * I_) + n0 + c4];
  tile[r][c4 + 0] = v.x; tile[r][c4 + 1] = v.y;
  tile[r][c4 + 2] = v.z; tile[r][c4 + 3] = v.w;
  __syncthreads();

  const int n = n0 + r;            // absolute col in 2I
  int np;
  if (n < I_) np = ((n >> 4) << 5) + (n & 15);
  else { const int j = n - I_; np = ((j >> 4) << 5) + 16 + (j & 15); }

  ushort4 o;
  o.x = f2bf(tile[c4 + 0][r]);
  o.y = f2bf(tile[c4 + 1][r]);
  o.z = f2bf(tile[c4 + 2][r]);
  o.w = f2bf(tile[c4 + 3][r]);
  *(ushort4*)&dst[dbase + (long)np * H_ + k0 + c4] = o;
}

// ---------------------------------------------------------------------------
// 256x256 8-phase GEMM, BK=64, 8 waves (2Mx4N), wave tile 128x64.
// LDS 128KB: A[2 buf][256 st-rows][64], B[2 buf][256 st-rows][64], bf16.
// Storage-row reorder: A st = ph*128 + wid*64 + w  (src row = wid*128+ph*64+w)
//                      B st = nh*128 + wid*32 + w  (src row = wid*64+nh*32+w)
// so each phase's operand half is one contiguous 16KB staging unit (2 gloads).
// XOR swizzle (T2): 16B slot s at storage row st holds global slot s^(st&7).
// Phases: P0 reads Aq0+Bq0, P1 Bq1, P2 Aq1, P3 none (b0 kept in regs).
// Stages: P0 Bq0(t+1)->buf^1; P1 Aq0(t+2)->buf; P2 Bq1(t+2)->buf;
//         P3 Aq1(t+2)->buf, then the single per-tile s_waitcnt vmcnt(6).
// ---------------------------------------------------------------------------
template <int K, int NBN, bool SILU>
__global__ __launch_bounds__(512, 2)
void gemm_8ph(const unsigned short* __restrict__ Aall,
              const unsigned short* __restrict__ Ball,
              void* __restrict__ Cout,
              long sA, long sB, long sC) {
  extern __shared__ char smem[];
  constexpr int NT = K / 64;

  const int tid  = threadIdx.x;
  const int wave = tid >> 6;
  const int lane = tid & 63;
  const int lr   = lane & 15;
  const int lq   = lane >> 4;
  const int wid_m = wave >> 2;     // 0..1
  const int wid_n = wave & 3;      // 0..3

  // T1: bijective XCD swizzle (gridDim.x % 8 == 0), mb innermost so the 4
  // m-blocks sharing one B panel are consecutive -> same XCD L2.
  const int nwg = gridDim.x;
  const int bid = blockIdx.x;
  const int wg  = (bid & 7) * (nwg >> 3) + (bid >> 3);
  const int mb  = wg & 3;
  const int tmp = wg >> 2;
  const int nb  = tmp % NBN;
  const int e   = tmp / NBN;

  const unsigned short* A = Aall + (long)e * sA + (long)(mb * 256) * K;
  const unsigned short* B = Ball + (long)e * sB + (long)(nb * 256) * K;

  // staging constants: lane slot s = tid&7, storage row-in-chunk = tid>>3
  const int stl  = tid >> 3;                      // 0..63
  const int scol = ((tid & 7) ^ (stl & 7)) * 8;   // pre-swizzled src element col

  auto stageA = [&](int bi, int q, int kt) {
    const long col = (long)kt * 64 + scol;
    char* l0 = smem + bi * 32768 + q * 16384 + wave * 1024;
    async16(A + (long)(q * 64 + stl) * K + col,        l0);
    async16(A + (long)(128 + q * 64 + stl) * K + col,  l0 + 8192);
  };
  auto stageB = [&](int bi, int u, int kt) {
    const long col = (long)kt * 64 + scol;
    char* l0 = smem + 65536 + bi * 32768 + u * 16384 + wave * 1024;
    const int low = stl & 31;
    const int w0  = stl >> 5;   // 0..1
    async16(B + (long)((w0) * 64 + u * 32 + low) * K + col,     l0);
    async16(B + (long)((2 + w0) * 64 + u * 32 + low) * K + col, l0 + 8192);
  };

  // fragment-read swizzled 16B-slot offsets (st&7 == lr&7 for all frags)
  const int ax0 = ((0 + lq) ^ (lr & 7)) * 16;   // ks=0
  const int ax1 = ((4 + lq) ^ (lr & 7)) * 16;   // ks=1

  f32x4 acc[8][4];
#pragma unroll
  for (int m = 0; m < 8; ++m)
#pragma unroll
    for (int n = 0; n < 4; ++n) acc[m][n] = (f32x4)0.0f;

  // prologue: prime 7 staging units (FIFO order matters for the ledger)
  stageA(0, 0, 0);
  stageB(0, 1, 0);
  stageA(0, 1, 0);
  stageB(0, 0, 0);
  stageA(1, 0, NT > 1 ? 1 : 0);
  stageB(1, 1, NT > 1 ? 1 : 0);
  stageA(1, 1, NT > 1 ? 1 : 0);
  asm volatile("s_waitcnt vmcnt(6)" ::: "memory");
  __builtin_amdgcn_s_barrier();

#pragma unroll 1
  for (int t = 0; t < NT; ++t) {
    const int cur = t & 1;
    const char* LA = smem + cur * 32768;
    const char* LB = smem + 65536 + cur * 32768;
    const int t1v = (t + 1 < NT) ? t + 1 : NT - 1;
    const int t2v = (t + 2 < NT) ? t + 2 : NT - 1;
    const int bo  = cur ^ 1;

    bf16x8 a[4][2], b0[2][2], b1[2][2];

    // ---------------- P0: read Aq0 + Bq0; stage Bq0(t+1) -> other buf ----
#pragma unroll
    for (int mf = 0; mf < 4; ++mf) {
      const int st = wid_m * 64 + mf * 16 + lr;
      a[mf][0] = *(const bf16x8*)(LA + st * 128 + ax0);
      a[mf][1] = *(const bf16x8*)(LA + st * 128 + ax1);
    }
#pragma unroll
    for (int nf = 0; nf < 2; ++nf) {
      const int st = wid_n * 32 + nf * 16 + lr;
      b0[nf][0] = *(const bf16x8*)(LB + st * 128 + ax0);
      b0[nf][1] = *(const bf16x8*)(LB + st * 128 + ax1);
    }
    stageB(bo, 0, t1v);
    __builtin_amdgcn_s_barrier();
    asm volatile("s_waitcnt lgkmcnt(0)" ::: "memory");
    __builtin_amdgcn_s_setprio(1);
#pragma unroll
    for (int mf = 0; mf < 4; ++mf)
#pragma unroll
      for (int nf = 0; nf < 2; ++nf) {
        acc[mf][nf] = __builtin_amdgcn_mfma_f32_16x16x32_bf16(a[mf][0], b0[nf][0], acc[mf][nf], 0, 0, 0);
        acc[mf][nf] = __builtin_amdgcn_mfma_f32_16x16x32_bf16(a[mf][1], b0[nf][1], acc[mf][nf], 0, 0, 0);
      }
    __builtin_amdgcn_s_setprio(0);
    __builtin_amdgcn_s_barrier();

    // ---------------- P1: read Bq1; stage Aq0(t+2) -> cur buf ------------
#pragma unroll
    for (int nf = 0; nf < 2; ++nf) {
      const int st = 128 + wid_n * 32 + nf * 16 + lr;
      b1[nf][0] = *(const bf16x8*)(LB + st * 128 + ax0);
      b1[nf][1] = *(const bf16x8*)(LB + st * 128 + ax1);
    }
    stageA(cur, 0, t2v);
    __builtin_amdgcn_s_barrier();
    asm volatile("s_waitcnt lgkmcnt(0)" ::: "memory");
    __builtin_amdgcn_s_setprio(1);
#pragma unroll
    for (int mf = 0; mf < 4; ++mf)
#pragma unroll
      for (int nf = 0; nf < 2; ++nf) {
        acc[mf][2 + nf] = __builtin_amdgcn_mfma_f32_16x16x32_bf16(a[mf][0], b1[nf][0], acc[mf][2 + nf], 0, 0, 0);
        acc[mf][2 + nf] = __builtin_amdgcn_mfma_f32_16x16x32_bf16(a[mf][1], b1[nf][1], acc[mf][2 + nf], 0, 0, 0);
      }
    __builtin_amdgcn_s_setprio(0);
    __builtin_amdgcn_s_barrier();

    // ---------------- P2: read Aq1 (overwrite a); stage Bq1(t+2) ---------
#pragma unroll
    for (int mf = 0; mf < 4; ++mf) {
      const int st = 128 + wid_m * 64 + mf * 16 + lr;
      a[mf][0] = *(const bf16x8*)(LA + st * 128 + ax0);
      a[mf][1] = *(const bf16x8*)(LA + st * 128 + ax1);
    }
    stageB(cur, 1, t2v);
    __builtin_amdgcn_s_barrier();
    asm volatile("s_waitcnt lgkmcnt(0)" ::: "memory");
    __builtin_amdgcn_s_setprio(1);
#pragma unroll
    for (int mf = 0; mf < 4; ++mf)
#pragma unroll
      for (int nf = 0; nf < 2; ++nf) {
        acc[4 + mf][2 + nf] = __builtin_amdgcn_mfma_f32_16x16x32_bf16(a[mf][0], b1[nf][0], acc[4 + mf][2 + nf], 0, 0, 0);
        acc[4 + mf][2 + nf] = __builtin_amdgcn_mfma_f32_16x16x32_bf16(a[mf][1], b1[nf][1], acc[4 + mf][2 + nf], 0, 0, 0);
      }
    __builtin_amdgcn_s_setprio(0);
    __builtin_amdgcn_s_barrier();

    // ---------------- P3: no reads (b0 in regs); stage Aq1(t+2); vmcnt(6)
    stageA(cur, 1, t2v);
    asm volatile("s_waitcnt vmcnt(6)" ::: "memory");
    __builtin_amdgcn_s_barrier();
    asm volatile("s_waitcnt lgkmcnt(0)" ::: "memory");
    __builtin_amdgcn_s_setprio(1);
#pragma unroll
    for (int mf = 0; mf < 4; ++mf)
#pragma unroll
      for (int nf = 0; nf < 2; ++nf) {
        acc[4 + mf][nf] = __builtin_amdgcn_mfma_f32_16x16x32_bf16(a[mf][0], b0[nf][0], acc[4 + mf][nf], 0, 0, 0);
        acc[4 + mf][nf] = __builtin_amdgcn_mfma_f32_16x16x32_bf16(a[mf][1], b0[nf][1], acc[4 + mf][nf], 0, 0, 0);
      }
    __builtin_amdgcn_s_setprio(0);
    __builtin_amdgcn_s_barrier();
  }

  // ---------------- epilogue (C/D: col=lane&15, row=(lane>>4)*4+r) -------
  if (SILU) {
    unsigned short* Cc = (unsigned short*)Cout + (long)e * sC;
    const int colbase = nb * 128 + wid_n * 32;
#pragma unroll
    for (int mf = 0; mf < 8; ++mf)
#pragma unroll
      for (int nfp = 0; nfp < 2; ++nfp)
#pragma unroll
        for (int rr = 0; rr < 4; ++rr) {
          const int row = mb * 256 + wid_m * 128 + mf * 16 + lq * 4 + rr;
          const int col = colbase + nfp * 16 + lr;
          const float g = acc[mf][nfp * 2][rr];
          const float u = acc[mf][nfp * 2 + 1][rr];
          Cc[(long)row * I_ + col] = f2bf(u * (g / (1.0f + __expf(-g))));
        }
  } else {
    float* Cc = (float*)Cout + (long)e * sC;
    const int colbase = nb * 256 + wid_n * 64;
#pragma unroll
    for (int mf = 0; mf < 8; ++mf)
#pragma unroll
      for (int nf = 0; nf < 4; ++nf)
#pragma unroll
        for (int rr = 0; rr < 4; ++rr) {
          const int row = mb * 256 + wid_m * 128 + mf * 16 + lq * 4 + rr;
          const int col = colbase + nf * 16 + lr;
          Cc[(long)row * H_ + col] = acc[mf][nf][rr];
        }
  }
}

// ---------------------------------------------------------------------------
extern "C" void kernel_launch(void* const* d_in, const int* in_sizes, int n_in,
                              void* d_out, int out_size, void* d_ws, size_t ws_size,
                              hipStream_t stream) {
  const float* hs = (const float*)d_in[0];   // (8192, 2048)
  const float* w1 = (const float*)d_in[1];   // (8, 2048, 8192)
  const float* w2 = (const float*)d_in[2];   // (8, 4096, 2048)
  float* out = (float*)d_out;                // (8192, 2048) fp32
  char* ws = (char*)d_ws;

  const long HB_B  = (long)T_ * H_ * 2;            //  32 MiB
  const long ACT_B = (long)T_ * I_ * 2;            //  64 MiB
  const long W1T_B = (long)E_ * 2 * I_ * H_ * 2;   // 256 MiB
  const long W2T_B = (long)E_ * H_ * I_ * 2;       // 128 MiB
  if (ws_size < (size_t)(HB_B + ACT_B + W1T_B + W2T_B)) return;

  unsigned short* hiddenB = (unsigned short*)(ws);
  unsigned short* acted   = (unsigned short*)(ws + HB_B);
  unsigned short* W1t     = (unsigned short*)(ws + HB_B + ACT_B);
  unsigned short* W2t     = (unsigned short*)(ws + HB_B + ACT_B + W1T_B);

  hipLaunchKernelGGL(convert_bf16, dim3(2048), dim3(256), 0, stream,
                     hs, hiddenB, (long)T_ * H_);
  hipLaunchKernelGGL(transpose_w1_perm, dim3((2 * I_) / 32, H_ / 32, E_), dim3(256), 0, stream,
                     w1, W1t);
  hipLaunchKernelGGL(transpose_bf16, dim3(H_ / 32, I_ / 32, E_), dim3(256), 0, stream,
                     w2, W2t, I_, H_);

  hipLaunchKernelGGL((gemm_8ph<H_, 32, true>), dim3(1024), dim3(512), 131072, stream,
                     hiddenB, W1t, acted,
                     (long)TPE * H_, (long)2 * I_ * H_, (long)TPE * I_);
  hipLaunchKernelGGL((gemm_8ph<I_, 8, false>), dim3(256), dim3(512), 131072, stream,
                     acted, W2t, out,
                     (long)TPE * I_, (long)H_ * I_, (long)TPE * H_);
}

// Round 3
// 604.215 us; speedup vs baseline: 1.3787x; 1.0265x over previous
//
#include <hip/hip_runtime.h>

// ---------------------------------------------------------------------------
// Llama4TextExperts: per-expert  out = (up * silu(gate)) @ W2
// E=8, T=8192 (1024/expert), H=2048, I=4096, fp32 in/out, bf16 MFMA compute.
// R3: weights read DIRECTLY as fp32 inside the GEMM (reg-staged transpose +
//     convert + swizzled ds_write), killing the 480MB transpose prepass.
//     A (activations) stays on the async global_load_lds path.
// ---------------------------------------------------------------------------

#define E_   8
#define H_   2048
#define I_   4096
#define T_   8192
#define TPE  1024

typedef __bf16 bf16x8 __attribute__((ext_vector_type(8)));
typedef float  f32x4  __attribute__((ext_vector_type(4)));

__device__ __forceinline__ unsigned short f2bf(float f) {
  union { float f; unsigned int u; } v; v.f = f;
  unsigned int u = v.u;
  u += 0x7FFFu + ((u >> 16) & 1u);   // RNE
  return (unsigned short)(u >> 16);
}

__device__ __forceinline__ void async16(const void* g, void* l) {
  __builtin_amdgcn_global_load_lds(
      (__attribute__((address_space(1))) void*)(g),
      (__attribute__((address_space(3))) void*)(l), 16, 0, 0);
}

#define SB0()    __builtin_amdgcn_sched_barrier(0)
#define BAR()    __builtin_amdgcn_s_barrier()
#define WAITLGKM() asm volatile("s_waitcnt lgkmcnt(0)" ::: "memory")
#define WAITVM(n)  asm volatile("s_waitcnt vmcnt(" #n ")" ::: "memory")

// ---------------------------------------------------------------------------
__global__ void convert_bf16(const float* __restrict__ src,
                             unsigned short* __restrict__ dst, long n) {
  long i = ((long)blockIdx.x * blockDim.x + threadIdx.x) * 4;
  const long stride = (long)gridDim.x * blockDim.x * 4;
  for (; i < n; i += stride) {
    const float4 v = *(const float4*)&src[i];
    ushort4 o;
    o.x = f2bf(v.x); o.y = f2bf(v.y); o.z = f2bf(v.z); o.w = f2bf(v.w);
    *(ushort4*)&dst[i] = o;
  }
}

// ---------------------------------------------------------------------------
// 256x256x64 8-phase GEMM. A: bf16 (M,K) via global_load_lds (linear dest,
// pre-swizzled source). B: fp32 (K,N) global, reg-staged: 8 K-strided dwords
// per lane (coalesced across lanes), cvt->bf16x8, swizzled ds_write_b128.
// LDS 128KB: A[2][256 rows][64] bf16 + B[2][256 rows][64] bf16.
// B storage row st (0..255) maps to global col via colOf(st) below; the
// fragment-read side (st = wid_n*32 + nf*16 + lr, +128 for b1) and epilogue
// use the inverse mapping.
// vmcnt ledger (per-thread issue order per tile):
//   P0: 16 dw B(t+1) | P1: 2 a16 A(t+2)q0 | P2: 16 dw B(t+1) | P3: 2 a16 q1
//   P2: vmcnt(2) -> drains [prev P3 a16][dw g1]; write g1 -> buf^1
//   P3: vmcnt(2) -> drains [P1 a16][dw g2];   write g2 -> buf^1; lgkm0; bar
// ---------------------------------------------------------------------------
template <int K, int NBN, int LDB, bool SILU>
__global__ __launch_bounds__(512, 2)
void gemm_fused(const unsigned short* __restrict__ Aall,
                const float* __restrict__ Ball,
                void* __restrict__ Cout,
                long sA, long sB, long sC) {
  extern __shared__ char smem[];
  constexpr int NT = K / 64;

  const int tid  = threadIdx.x;
  const int wave = tid >> 6;
  const int lane = tid & 63;
  const int lr   = lane & 15;
  const int lq   = lane >> 4;
  const int wid_m = wave >> 2;     // 0..1
  const int wid_n = wave & 3;      // 0..3

  // T1: bijective XCD swizzle (gridDim.x % 8 == 0), mb innermost.
  const int nwg = gridDim.x;
  const int bid = blockIdx.x;
  const int wg  = (bid & 7) * (nwg >> 3) + (bid >> 3);
  const int mb  = wg & 3;
  const int tmp = wg >> 2;
  const int nb  = tmp % NBN;
  const int e   = tmp / NBN;

  const unsigned short* A = Aall + (long)e * sA + (long)(mb * 256) * K;
  const float*          B = Ball + (long)e * sB;

  // ---- A staging (unchanged from R2, global_load_lds + pre-swizzled src)
  const int stl  = tid >> 3;                      // 0..63
  const int scol = ((tid & 7) ^ (stl & 7)) * 8;   // swizzled src elem col

  auto stageA = [&](int bi, int q, int kt) {
    const long col = (long)kt * 64 + scol;
    char* l0 = smem + bi * 32768 + q * 16384 + wave * 1024;
    async16(A + (long)(q * 64 + stl) * K + col,        l0);
    async16(A + (long)(128 + q * 64 + stl) * K + col,  l0 + 8192);
  };

  // ---- B reg-staging: thread owns ONE column (st = tid&255) and k-octets
  //      ko = u*2 + (tid>>8), u=0..3.  col mapping st -> global column:
  const int stB = tid & 255;
  int colg;
  {
    const int b  = stB >> 7;
    const int r  = stB & 127;
    const int w  = r >> 5;
    const int nf = (r >> 4) & 1;
    const int l4 = stB & 15;
    if (SILU) {
      const int c = w * 32 + b * 16 + l4;          // local acted col (128)
      colg = nb * 128 + c + (nf ? I_ : 0);         // gate or up column
    } else {
      colg = nb * 256 + w * 64 + (b * 2 + nf) * 16 + l4;
    }
  }
  const float* Bp = B + colg;
  const int koB = tid >> 8;                        // 0..1

  float bv[16];
  auto loadB = [&](int g, int kt) {
#pragma unroll
    for (int uu = 0; uu < 2; ++uu) {
      const int ko = (g * 2 + uu) * 2 + koB;       // 0..7
      const long krow = (long)kt * 64 + ko * 8;
#pragma unroll
      for (int j = 0; j < 8; ++j)
        bv[uu * 8 + j] = Bp[(krow + j) * (long)LDB];
    }
  };
  auto writeB = [&](int bo, int g) {
    char* LB = smem + 65536 + bo * 32768;
#pragma unroll
    for (int uu = 0; uu < 2; ++uu) {
      const int ko = (g * 2 + uu) * 2 + koB;
      bf16x8 pk;
#pragma unroll
      for (int j = 0; j < 8; ++j) pk[j] = (__bf16)bv[uu * 8 + j];
      *(bf16x8*)(LB + stB * 128 + ((ko ^ (stB & 7)) * 16)) = pk;
    }
  };

  // fragment-read swizzled 16B-slot offsets (st&7 == lr&7 for all frags)
  const int ax0 = ((0 + lq) ^ (lr & 7)) * 16;   // k-slot group 0 (k 0..31)
  const int ax1 = ((4 + lq) ^ (lr & 7)) * 16;   // k-slot group 1 (k 32..63)

  f32x4 acc[8][4];
#pragma unroll
  for (int m = 0; m < 8; ++m)
#pragma unroll
    for (int n = 0; n < 4; ++n) acc[m][n] = (f32x4)0.0f;

  // ---------------- prologue --------------------------------------------
  const int t1p = (NT > 1) ? 1 : 0;
  loadB(0, 0);                 // 16 dw  (B t0, k 0..31)
  stageA(0, 0, 0);             // 2 a16
  stageA(0, 1, 0);             // 2 a16
  SB0();
  WAITVM(4);                   // dw g1 done (leaves 4 a16 A(t0))
  writeB(0, 0);
  loadB(1, 0);                 // 16 dw  (B t0, k 32..63)
  stageA(1, 0, t1p);           // 2 a16
  stageA(1, 1, t1p);           // 2 a16
  SB0();
  WAITVM(4);                   // A(t0)+dw g2 done (leaves 4 a16 A(t1))
  writeB(0, 1);
  WAITLGKM();
  BAR();

#pragma unroll 1
  for (int t = 0; t < NT; ++t) {
    const int cur = t & 1;
    const int bo  = cur ^ 1;
    const char* LA = smem + cur * 32768;
    const char* LB = smem + 65536 + cur * 32768;
    const int t1v = (t + 1 < NT) ? t + 1 : NT - 1;
    const int t2v = (t + 2 < NT) ? t + 2 : NT - 1;

    bf16x8 a[4][2], b0[2][2], b1[2][2];

    // ---- P0: read a(q0)+b0; issue B dwords g1(t+1) ----------------------
#pragma unroll
    for (int mf = 0; mf < 4; ++mf) {
      const int st = wid_m * 64 + mf * 16 + lr;
      a[mf][0] = *(const bf16x8*)(LA + st * 128 + ax0);
      a[mf][1] = *(const bf16x8*)(LA + st * 128 + ax1);
    }
#pragma unroll
    for (int nf = 0; nf < 2; ++nf) {
      const int st = wid_n * 32 + nf * 16 + lr;
      b0[nf][0] = *(const bf16x8*)(LB + st * 128 + ax0);
      b0[nf][1] = *(const bf16x8*)(LB + st * 128 + ax1);
    }
    loadB(0, t1v);
    SB0();
    BAR();
    WAITLGKM();
    __builtin_amdgcn_s_setprio(1);
#pragma unroll
    for (int mf = 0; mf < 4; ++mf)
#pragma unroll
      for (int nf = 0; nf < 2; ++nf) {
        acc[mf][nf] = __builtin_amdgcn_mfma_f32_16x16x32_bf16(a[mf][0], b0[nf][0], acc[mf][nf], 0, 0, 0);
        acc[mf][nf] = __builtin_amdgcn_mfma_f32_16x16x32_bf16(a[mf][1], b0[nf][1], acc[mf][nf], 0, 0, 0);
      }
    __builtin_amdgcn_s_setprio(0);
    BAR();

    // ---- P1: read b1; stage A(t+2) q0 ----------------------------------
#pragma unroll
    for (int nf = 0; nf < 2; ++nf) {
      const int st = 128 + wid_n * 32 + nf * 16 + lr;
      b1[nf][0] = *(const bf16x8*)(LB + st * 128 + ax0);
      b1[nf][1] = *(const bf16x8*)(LB + st * 128 + ax1);
    }
    stageA(cur, 0, t2v);
    SB0();
    BAR();
    WAITLGKM();
    __builtin_amdgcn_s_setprio(1);
#pragma unroll
    for (int mf = 0; mf < 4; ++mf)
#pragma unroll
      for (int nf = 0; nf < 2; ++nf) {
        acc[mf][2 + nf] = __builtin_amdgcn_mfma_f32_16x16x32_bf16(a[mf][0], b1[nf][0], acc[mf][2 + nf], 0, 0, 0);
        acc[mf][2 + nf] = __builtin_amdgcn_mfma_f32_16x16x32_bf16(a[mf][1], b1[nf][1], acc[mf][2 + nf], 0, 0, 0);
      }
    __builtin_amdgcn_s_setprio(0);
    BAR();

    // ---- P2: read a(q1); vmcnt(2) -> write B g1(t+1); issue dwords g2 --
#pragma unroll
    for (int mf = 0; mf < 4; ++mf) {
      const int st = 128 + wid_m * 64 + mf * 16 + lr;
      a[mf][0] = *(const bf16x8*)(LA + st * 128 + ax0);
      a[mf][1] = *(const bf16x8*)(LA + st * 128 + ax1);
    }
    WAITVM(2);                 // drains [prev P3 a16][dw g1]; leaves P1 a16
    writeB(bo, 0);
    loadB(1, t1v);
    SB0();
    BAR();
    WAITLGKM();
    __builtin_amdgcn_s_setprio(1);
#pragma unroll
    for (int mf = 0; mf < 4; ++mf)
#pragma unroll
      for (int nf = 0; nf < 2; ++nf) {
        acc[4 + mf][2 + nf] = __builtin_amdgcn_mfma_f32_16x16x32_bf16(a[mf][0], b1[nf][0], acc[4 + mf][2 + nf], 0, 0, 0);
        acc[4 + mf][2 + nf] = __builtin_amdgcn_mfma_f32_16x16x32_bf16(a[mf][1], b1[nf][1], acc[4 + mf][2 + nf], 0, 0, 0);
      }
    __builtin_amdgcn_s_setprio(0);
    BAR();

    // ---- P3: stage A(t+2) q1; vmcnt(2) -> write B g2(t+1); lgkm0; bar --
    stageA(cur, 1, t2v);
    SB0();
    WAITVM(2);                 // drains [P1 a16][dw g2]; leaves P3 a16
    writeB(bo, 1);
    WAITLGKM();                // publish ds_writes before barrier
    BAR();
    __builtin_amdgcn_s_setprio(1);
#pragma unroll
    for (int mf = 0; mf < 4; ++mf)
#pragma unroll
      for (int nf = 0; nf < 2; ++nf) {
        acc[4 + mf][nf] = __builtin_amdgcn_mfma_f32_16x16x32_bf16(a[mf][0], b0[nf][0], acc[4 + mf][nf], 0, 0, 0);
        acc[4 + mf][nf] = __builtin_amdgcn_mfma_f32_16x16x32_bf16(a[mf][1], b0[nf][1], acc[4 + mf][nf], 0, 0, 0);
      }
    __builtin_amdgcn_s_setprio(0);
    BAR();
  }

  // ---------------- epilogue (C/D: col=lane&15, row=(lane>>4)*4+r) -------
  const int lqq = lane >> 4;
  if (SILU) {
    unsigned short* Cc = (unsigned short*)Cout + (long)e * sC;
#pragma unroll
    for (int mf = 0; mf < 8; ++mf)
#pragma unroll
      for (int p = 0; p < 2; ++p)
#pragma unroll
        for (int rr = 0; rr < 4; ++rr) {
          const int row = mb * 256 + wid_m * 128 + mf * 16 + lqq * 4 + rr;
          const int col = nb * 128 + wid_n * 32 + p * 16 + lr;
          const float g = acc[mf][p * 2][rr];
          const float u = acc[mf][p * 2 + 1][rr];
          Cc[(long)row * I_ + col] = f2bf(u * (g / (1.0f + __expf(-g))));
        }
  } else {
    float* Cc = (float*)Cout + (long)e * sC;
#pragma unroll
    for (int mf = 0; mf < 8; ++mf)
#pragma unroll
      for (int q = 0; q < 4; ++q)
#pragma unroll
        for (int rr = 0; rr < 4; ++rr) {
          const int row = mb * 256 + wid_m * 128 + mf * 16 + lqq * 4 + rr;
          const int col = nb * 256 + wid_n * 64 + q * 16 + lr;
          Cc[(long)row * H_ + col] = acc[mf][q][rr];
        }
  }
}

// ---------------------------------------------------------------------------
extern "C" void kernel_launch(void* const* d_in, const int* in_sizes, int n_in,
                              void* d_out, int out_size, void* d_ws, size_t ws_size,
                              hipStream_t stream) {
  const float* hs = (const float*)d_in[0];   // (8192, 2048)
  const float* w1 = (const float*)d_in[1];   // (8, 2048, 8192)
  const float* w2 = (const float*)d_in[2];   // (8, 4096, 2048)
  float* out = (float*)d_out;                // (8192, 2048) fp32
  char* ws = (char*)d_ws;

  const long HB_B  = (long)T_ * H_ * 2;      // 32 MiB hidden bf16
  const long ACT_B = (long)T_ * I_ * 2;      // 64 MiB acted bf16
  if (ws_size < (size_t)(HB_B + ACT_B)) return;

  unsigned short* hiddenB = (unsigned short*)(ws);
  unsigned short* acted   = (unsigned short*)(ws + HB_B);

  hipLaunchKernelGGL(convert_bf16, dim3(2048), dim3(256), 0, stream,
                     hs, hiddenB, (long)T_ * H_);

  // gemm1+SiLU: A=hiddenB (TPE,H), B=W1 (H,2I) fp32 direct -> acted bf16
  hipLaunchKernelGGL((gemm_fused<H_, 32, 2 * I_, true>),
                     dim3(1024), dim3(512), 131072, stream,
                     hiddenB, w1, acted,
                     (long)TPE * H_, (long)H_ * 2 * I_, (long)TPE * I_);

  // gemm2: A=acted (TPE,I), B=W2 (I,H) fp32 direct -> out fp32
  hipLaunchKernelGGL((gemm_fused<I_, 8, H_, false>),
                     dim3(256), dim3(512), 131072, stream,
                     acted, w2, out,
                     (long)TPE * I_, (long)I_ * H_, (long)TPE * H_);
}

// Round 4
// 585.337 us; speedup vs baseline: 1.4232x; 1.0323x over previous
//
#include <hip/hip_runtime.h>

// ---------------------------------------------------------------------------
// Llama4TextExperts: per-expert  out = (up * silu(gate)) @ W2
// E=8, T=8192 (1024/expert), H=2048, I=4096, fp32 in/out, bf16 MFMA compute.
// R4: deep B reg-pipeline — B fp32 loads issued at P2/P3(t) for tile t+2,
//     written to LDS at P2/P3(t+1): 4 MFMA clusters of latency cover
//     (R3 had only ~2). Two 16-float slots keep VGPR in budget.
// ---------------------------------------------------------------------------

#define E_   8
#define H_   2048
#define I_   4096
#define T_   8192
#define TPE  1024

typedef __bf16 bf16x8 __attribute__((ext_vector_type(8)));
typedef float  f32x4  __attribute__((ext_vector_type(4)));

__device__ __forceinline__ unsigned short f2bf(float f) {
  union { float f; unsigned int u; } v; v.f = f;
  unsigned int u = v.u;
  u += 0x7FFFu + ((u >> 16) & 1u);   // RNE
  return (unsigned short)(u >> 16);
}

__device__ __forceinline__ void async16(const void* g, void* l) {
  __builtin_amdgcn_global_load_lds(
      (__attribute__((address_space(1))) void*)(g),
      (__attribute__((address_space(3))) void*)(l), 16, 0, 0);
}

#define SB0()      __builtin_amdgcn_sched_barrier(0)
#define BAR()      __builtin_amdgcn_s_barrier()
#define WAITLGKM() asm volatile("s_waitcnt lgkmcnt(0)" ::: "memory")
#define WAITVM(n)  asm volatile("s_waitcnt vmcnt(" #n ")" ::: "memory")

// ---------------------------------------------------------------------------
__global__ void convert_bf16(const float* __restrict__ src,
                             unsigned short* __restrict__ dst, long n) {
  long i = ((long)blockIdx.x * blockDim.x + threadIdx.x) * 4;
  const long stride = (long)gridDim.x * blockDim.x * 4;
  for (; i < n; i += stride) {
    const float4 v = *(const float4*)&src[i];
    ushort4 o;
    o.x = f2bf(v.x); o.y = f2bf(v.y); o.z = f2bf(v.z); o.w = f2bf(v.w);
    *(ushort4*)&dst[i] = o;
  }
}

// ---------------------------------------------------------------------------
// 256x256x64 8-phase GEMM. A: bf16 (M,K) via global_load_lds (linear dest,
// pre-swizzled source). B: fp32 (K,N) global, reg-staged 2 tiles ahead:
//   tile t: P1 issues A(t+2)q0 [2 a16]; P2 issues B(t+2)g1 [16 dw];
//           P3 issues A(t+2)q1 [2 a16] + B(t+2)g2 [16 dw].
//   B(t+1) groups written to LDS at P2(t)/P3(t) after vmcnt(20)/vmcnt(20).
// LDS 128KB: A[2][256][64] bf16 + B[2][256][64] bf16, XOR-swizzled 16B slots.
// ---------------------------------------------------------------------------
template <int K, int NBN, int LDB, bool SILU>
__global__ __launch_bounds__(512, 2)
void gemm_fused(const unsigned short* __restrict__ Aall,
                const float* __restrict__ Ball,
                void* __restrict__ Cout,
                long sA, long sB, long sC) {
  extern __shared__ char smem[];
  constexpr int NT = K / 64;

  const int tid  = threadIdx.x;
  const int wave = tid >> 6;
  const int lane = tid & 63;
  const int lr   = lane & 15;
  const int lq   = lane >> 4;
  const int wid_m = wave >> 2;     // 0..1
  const int wid_n = wave & 3;      // 0..3

  // T1: bijective XCD swizzle (gridDim.x % 8 == 0), mb innermost.
  const int nwg = gridDim.x;
  const int bid = blockIdx.x;
  const int wg  = (bid & 7) * (nwg >> 3) + (bid >> 3);
  const int mb  = wg & 3;
  const int tmp = wg >> 2;
  const int nb  = tmp % NBN;
  const int e   = tmp / NBN;

  const unsigned short* A = Aall + (long)e * sA + (long)(mb * 256) * K;
  const float*          B = Ball + (long)e * sB;

  // ---- A staging (global_load_lds, pre-swizzled source) ------------------
  const int stl  = tid >> 3;                      // 0..63
  const int scol = ((tid & 7) ^ (stl & 7)) * 8;   // swizzled src elem col

  auto stageA = [&](int bi, int q, int kt) {
    const long col = (long)kt * 64 + scol;
    char* l0 = smem + bi * 32768 + q * 16384 + wave * 1024;
    async16(A + (long)(q * 64 + stl) * K + col,        l0);
    async16(A + (long)(128 + q * 64 + stl) * K + col,  l0 + 8192);
  };

  // ---- B reg-staging: thread owns ONE column (st = tid&255), k-octets ----
  const int stB = tid & 255;
  int colg;
  {
    const int b  = stB >> 7;
    const int r  = stB & 127;
    const int w  = r >> 5;
    const int nf = (r >> 4) & 1;
    const int l4 = stB & 15;
    if (SILU) {
      const int c = w * 32 + b * 16 + l4;          // local acted col (128)
      colg = nb * 128 + c + (nf ? I_ : 0);         // gate or up column
    } else {
      colg = nb * 256 + w * 64 + (b * 2 + nf) * 16 + l4;
    }
  }
  const float* Bp = B + colg;
  const int koB = tid >> 8;                        // 0..1

  float bvG1[16], bvG2[16];

#define LOADB(BV, G, KT)                                                    \
  do {                                                                      \
    _Pragma("unroll")                                                       \
    for (int uu = 0; uu < 2; ++uu) {                                        \
      const int ko_ = ((G) * 2 + uu) * 2 + koB;                             \
      const float* p_ = Bp + ((long)(KT) * 64 + ko_ * 8) * (long)LDB;       \
      _Pragma("unroll")                                                     \
      for (int j = 0; j < 8; ++j) BV[uu * 8 + j] = p_[j * (long)LDB];       \
    }                                                                       \
  } while (0)

#define WRITEB(BO, BV, G)                                                   \
  do {                                                                      \
    char* LBw_ = smem + 65536 + (BO) * 32768;                               \
    _Pragma("unroll")                                                       \
    for (int uu = 0; uu < 2; ++uu) {                                        \
      const int ko_ = ((G) * 2 + uu) * 2 + koB;                             \
      bf16x8 pk_;                                                           \
      _Pragma("unroll")                                                     \
      for (int j = 0; j < 8; ++j) pk_[j] = (__bf16)BV[uu * 8 + j];          \
      *(bf16x8*)(LBw_ + stB * 128 + ((ko_ ^ (stB & 7)) * 16)) = pk_;        \
    }                                                                       \
  } while (0)

  // fragment-read swizzled 16B-slot offsets (st&7 == lr&7 for all frags)
  const int ax0 = ((0 + lq) ^ (lr & 7)) * 16;   // k 0..31
  const int ax1 = ((4 + lq) ^ (lr & 7)) * 16;   // k 32..63

  f32x4 acc[8][4];
#pragma unroll
  for (int m = 0; m < 8; ++m)
#pragma unroll
    for (int n = 0; n < 4; ++n) acc[m][n] = (f32x4)0.0f;

  // ---------------- prologue --------------------------------------------
  const int t1p = (NT > 1) ? 1 : 0;
  LOADB(bvG1, 0, 0);           // D1(0) 16 dw
  LOADB(bvG2, 1, 0);           // D2(0) 16 dw
  stageA(0, 0, 0);             // 2 a16
  stageA(0, 1, 0);             // 2 a16
  SB0();
  WAITVM(20); SB0();           // D1(0) done (leaves D2(0)16 + A4)
  WRITEB(0, bvG1, 0);
  WAITVM(4); SB0();            // D2(0) done (leaves A4)
  WRITEB(0, bvG2, 1);
  WAITLGKM(); SB0();           // publish B(0); free bv slots (WAR)
  stageA(1, 0, t1p); SB0();    // A1(1) 2
  LOADB(bvG1, 0, t1p); SB0();  // D1(1) 16
  stageA(1, 1, t1p); SB0();    // A2(1) 2
  LOADB(bvG2, 1, t1p); SB0();  // D2(1) 16
  WAITVM(36); SB0();           // drain A(0) stages; leaves [A1,D1,A2,D2](1)
  BAR();

#pragma unroll 1
  for (int t = 0; t < NT; ++t) {
    const int cur = t & 1;
    const int bo  = cur ^ 1;
    const char* LA = smem + cur * 32768;
    const char* LB = smem + 65536 + cur * 32768;
    const int t2v = (t + 2 < NT) ? t + 2 : NT - 1;

    bf16x8 a[4][2], b0[2][2], b1[2][2];

    // ---- P0: read a(q0)+b0; no VMEM ------------------------------------
#pragma unroll
    for (int mf = 0; mf < 4; ++mf) {
      const int st = wid_m * 64 + mf * 16 + lr;
      a[mf][0] = *(const bf16x8*)(LA + st * 128 + ax0);
      a[mf][1] = *(const bf16x8*)(LA + st * 128 + ax1);
    }
#pragma unroll
    for (int nf = 0; nf < 2; ++nf) {
      const int st = wid_n * 32 + nf * 16 + lr;
      b0[nf][0] = *(const bf16x8*)(LB + st * 128 + ax0);
      b0[nf][1] = *(const bf16x8*)(LB + st * 128 + ax1);
    }
    SB0();
    BAR();
    WAITLGKM(); SB0();
    __builtin_amdgcn_s_setprio(1);
#pragma unroll
    for (int mf = 0; mf < 4; ++mf)
#pragma unroll
      for (int nf = 0; nf < 2; ++nf) {
        acc[mf][nf] = __builtin_amdgcn_mfma_f32_16x16x32_bf16(a[mf][0], b0[nf][0], acc[mf][nf], 0, 0, 0);
        acc[mf][nf] = __builtin_amdgcn_mfma_f32_16x16x32_bf16(a[mf][1], b0[nf][1], acc[mf][nf], 0, 0, 0);
      }
    __builtin_amdgcn_s_setprio(0);
    BAR();

    // ---- P1: read b1; issue A(t+2)q0 -----------------------------------
#pragma unroll
    for (int nf = 0; nf < 2; ++nf) {
      const int st = 128 + wid_n * 32 + nf * 16 + lr;
      b1[nf][0] = *(const bf16x8*)(LB + st * 128 + ax0);
      b1[nf][1] = *(const bf16x8*)(LB + st * 128 + ax1);
    }
    stageA(cur, 0, t2v);
    SB0();
    BAR();
    WAITLGKM(); SB0();
    __builtin_amdgcn_s_setprio(1);
#pragma unroll
    for (int mf = 0; mf < 4; ++mf)
#pragma unroll
      for (int nf = 0; nf < 2; ++nf) {
        acc[mf][2 + nf] = __builtin_amdgcn_mfma_f32_16x16x32_bf16(a[mf][0], b1[nf][0], acc[mf][2 + nf], 0, 0, 0);
        acc[mf][2 + nf] = __builtin_amdgcn_mfma_f32_16x16x32_bf16(a[mf][1], b1[nf][1], acc[mf][2 + nf], 0, 0, 0);
      }
    __builtin_amdgcn_s_setprio(0);
    BAR();

    // ---- P2: read a(q1); vmcnt(20) -> write B g1(t+1); issue B g1(t+2) -
#pragma unroll
    for (int mf = 0; mf < 4; ++mf) {
      const int st = 128 + wid_m * 64 + mf * 16 + lr;
      a[mf][0] = *(const bf16x8*)(LA + st * 128 + ax0);
      a[mf][1] = *(const bf16x8*)(LA + st * 128 + ax1);
    }
    SB0();
    WAITVM(20); SB0();         // D1(t+1) done (A2,D2(t+1),A1(t+2) in flight)
    WRITEB(bo, bvG1, 0);
    WAITLGKM(); SB0();         // drain a(q1) reads + writeB; WAR-free slot
    LOADB(bvG1, 0, t2v);       // D1(t+2)
    SB0();
    BAR();
    __builtin_amdgcn_s_setprio(1);
#pragma unroll
    for (int mf = 0; mf < 4; ++mf)
#pragma unroll
      for (int nf = 0; nf < 2; ++nf) {
        acc[4 + mf][2 + nf] = __builtin_amdgcn_mfma_f32_16x16x32_bf16(a[mf][0], b1[nf][0], acc[4 + mf][2 + nf], 0, 0, 0);
        acc[4 + mf][2 + nf] = __builtin_amdgcn_mfma_f32_16x16x32_bf16(a[mf][1], b1[nf][1], acc[4 + mf][2 + nf], 0, 0, 0);
      }
    __builtin_amdgcn_s_setprio(0);
    BAR();

    // ---- P3: issue A(t+2)q1; vmcnt(20) -> write B g2(t+1); issue B g2 --
    stageA(cur, 1, t2v);
    SB0();
    WAITVM(20); SB0();         // D2(t+1) done (A1,D1,A2(t+2) in flight)
    WRITEB(bo, bvG2, 1);
    WAITLGKM(); SB0();         // publish both B groups; WAR-free slot
    LOADB(bvG2, 1, t2v);       // D2(t+2)
    SB0();
    BAR();
    __builtin_amdgcn_s_setprio(1);
#pragma unroll
    for (int mf = 0; mf < 4; ++mf)
#pragma unroll
      for (int nf = 0; nf < 2; ++nf) {
        acc[4 + mf][nf] = __builtin_amdgcn_mfma_f32_16x16x32_bf16(a[mf][0], b0[nf][0], acc[4 + mf][nf], 0, 0, 0);
        acc[4 + mf][nf] = __builtin_amdgcn_mfma_f32_16x16x32_bf16(a[mf][1], b0[nf][1], acc[4 + mf][nf], 0, 0, 0);
      }
    __builtin_amdgcn_s_setprio(0);
    BAR();
  }

  // ---------------- epilogue (C/D: col=lane&15, row=(lane>>4)*4+r) -------
  if (SILU) {
    unsigned short* Cc = (unsigned short*)Cout + (long)e * sC;
#pragma unroll
    for (int mf = 0; mf < 8; ++mf)
#pragma unroll
      for (int p = 0; p < 2; ++p)
#pragma unroll
        for (int rr = 0; rr < 4; ++rr) {
          const int row = mb * 256 + wid_m * 128 + mf * 16 + lq * 4 + rr;
          const int col = nb * 128 + wid_n * 32 + p * 16 + lr;
          const float g = acc[mf][p * 2][rr];
          const float u = acc[mf][p * 2 + 1][rr];
          Cc[(long)row * I_ + col] = f2bf(u * (g / (1.0f + __expf(-g))));
        }
  } else {
    float* Cc = (float*)Cout + (long)e * sC;
#pragma unroll
    for (int mf = 0; mf < 8; ++mf)
#pragma unroll
      for (int q = 0; q < 4; ++q)
#pragma unroll
        for (int rr = 0; rr < 4; ++rr) {
          const int row = mb * 256 + wid_m * 128 + mf * 16 + lq * 4 + rr;
          const int col = nb * 256 + wid_n * 64 + q * 16 + lr;
          Cc[(long)row * H_ + col] = acc[mf][q][rr];
        }
  }
#undef LOADB
#undef WRITEB
}

// ---------------------------------------------------------------------------
extern "C" void kernel_launch(void* const* d_in, const int* in_sizes, int n_in,
                              void* d_out, int out_size, void* d_ws, size_t ws_size,
                              hipStream_t stream) {
  const float* hs = (const float*)d_in[0];   // (8192, 2048)
  const float* w1 = (const float*)d_in[1];   // (8, 2048, 8192)
  const float* w2 = (const float*)d_in[2];   // (8, 4096, 2048)
  float* out = (float*)d_out;                // (8192, 2048) fp32
  char* ws = (char*)d_ws;

  const long HB_B  = (long)T_ * H_ * 2;      // 32 MiB hidden bf16
  const long ACT_B = (long)T_ * I_ * 2;      // 64 MiB acted bf16
  if (ws_size < (size_t)(HB_B + ACT_B)) return;

  unsigned short* hiddenB = (unsigned short*)(ws);
  unsigned short* acted   = (unsigned short*)(ws + HB_B);

  hipLaunchKernelGGL(convert_bf16, dim3(2048), dim3(256), 0, stream,
                     hs, hiddenB, (long)T_ * H_);

  // gemm1+SiLU: A=hiddenB (TPE,H), B=W1 (H,2I) fp32 direct -> acted bf16
  hipLaunchKernelGGL((gemm_fused<H_, 32, 2 * I_, true>),
                     dim3(1024), dim3(512), 131072, stream,
                     hiddenB, w1, acted,
                     (long)TPE * H_, (long)H_ * 2 * I_, (long)TPE * I_);

  // gemm2: A=acted (TPE,I), B=W2 (I,H) fp32 direct -> out fp32
  hipLaunchKernelGGL((gemm_fused<I_, 8, H_, false>),
                     dim3(256), dim3(512), 131072, stream,
                     acted, w2, out,
                     (long)TPE * I_, (long)I_ * H_, (long)TPE * H_);
}

// Round 5
// 525.208 us; speedup vs baseline: 1.5861x; 1.1145x over previous
//
#include <hip/hip_runtime.h>

// ---------------------------------------------------------------------------
// Llama4TextExperts: per-expert  out = (up * silu(gate)) @ W2
// E=8, T=8192 (1024/expert), H=2048, I=4096, fp32 in/out, bf16 MFMA compute.
// R5: B loaded as float4 along N (8 VMEM instr/thread/tile vs 32 scalars),
//     in-register transpose + cvt + conflict-free ds_write_b128 (quad-XOR
//     swizzle). Attacks the VMEM-issue bound R4 exposed.
// ---------------------------------------------------------------------------

#define E_   8
#define H_   2048
#define I_   4096
#define T_   8192
#define TPE  1024

typedef __bf16 bf16x8 __attribute__((ext_vector_type(8)));
typedef float  f32x4  __attribute__((ext_vector_type(4)));

__device__ __forceinline__ unsigned short f2bf(float f) {
  union { float f; unsigned int u; } v; v.f = f;
  unsigned int u = v.u;
  u += 0x7FFFu + ((u >> 16) & 1u);   // RNE
  return (unsigned short)(u >> 16);
}

__device__ __forceinline__ void async16(const void* g, void* l) {
  __builtin_amdgcn_global_load_lds(
      (__attribute__((address_space(1))) void*)(g),
      (__attribute__((address_space(3))) void*)(l), 16, 0, 0);
}

#define SB0()      __builtin_amdgcn_sched_barrier(0)
#define BAR()      __builtin_amdgcn_s_barrier()
#define WAITLGKM() asm volatile("s_waitcnt lgkmcnt(0)" ::: "memory")
#define WAITVM(n)  asm volatile("s_waitcnt vmcnt(" #n ")" ::: "memory")

// ---------------------------------------------------------------------------
__global__ void convert_bf16(const float* __restrict__ src,
                             unsigned short* __restrict__ dst, long n) {
  long i = ((long)blockIdx.x * blockDim.x + threadIdx.x) * 4;
  const long stride = (long)gridDim.x * blockDim.x * 4;
  for (; i < n; i += stride) {
    const float4 v = *(const float4*)&src[i];
    ushort4 o;
    o.x = f2bf(v.x); o.y = f2bf(v.y); o.z = f2bf(v.z); o.w = f2bf(v.w);
    *(ushort4*)&dst[i] = o;
  }
}

// ---------------------------------------------------------------------------
// 256x256x64 8-phase GEMM. A: bf16 (M,K) via global_load_lds (linear dest,
// pre-swizzled source, row-XOR &7 swizzle). B: fp32 (K,N), per-thread float4
// loads (lane owns 4 contiguous cols = 4 contiguous storage rows 4*lane..+3;
// wave = k-octet), reg transpose -> bf16x8 -> ds_write_b128 at
// slot = ko ^ ((st>>2)&7)  (conflict-free writes; 4-way b-frag reads).
// vmcnt ledger (per-thread/wave issue per tile):
//   P1: A q0(t+2) [2 a16] | P2: vmcnt(4) -> writeB(t+1), issue B(t+2) [8 f4]
//   P3: A q1(t+2) [2 a16], vmcnt(12)
// LDS 128KB: A[2][256][64] bf16 + B[2][256][64] bf16.
// ---------------------------------------------------------------------------
template <int K, int NBN, int LDB, bool SILU>
__global__ __launch_bounds__(512, 2)
void gemm_fused(const unsigned short* __restrict__ Aall,
                const float* __restrict__ Ball,
                void* __restrict__ Cout,
                long sA, long sB, long sC) {
  extern __shared__ char smem[];
  constexpr int NT = K / 64;

  const int tid  = threadIdx.x;
  const int wave = tid >> 6;
  const int lane = tid & 63;
  const int lr   = lane & 15;
  const int lq   = lane >> 4;
  const int wid_m = wave >> 2;     // 0..1
  const int wid_n = wave & 3;      // 0..3

  // T1: bijective XCD swizzle (gridDim.x % 8 == 0), mb innermost.
  const int nwg = gridDim.x;
  const int bid = blockIdx.x;
  const int wg  = (bid & 7) * (nwg >> 3) + (bid >> 3);
  const int mb  = wg & 3;
  const int tmp = wg >> 2;
  const int nb  = tmp % NBN;
  const int e   = tmp / NBN;

  const unsigned short* A = Aall + (long)e * sA + (long)(mb * 256) * K;
  const float*          B = Ball + (long)e * sB;

  // ---- A staging (global_load_lds, pre-swizzled source) ------------------
  const int stl  = tid >> 3;                      // 0..63
  const int scol = ((tid & 7) ^ (stl & 7)) * 8;   // swizzled src elem col

  auto stageA = [&](int bi, int q, int kt) {
    const long col = (long)kt * 64 + scol;
    char* l0 = smem + bi * 32768 + q * 16384 + wave * 1024;
    async16(A + (long)(q * 64 + stl) * K + col,        l0);
    async16(A + (long)(128 + q * 64 + stl) * K + col,  l0 + 8192);
  };

  // ---- B: lane owns storage rows 4*lane..4*lane+3 (contiguous global cols),
  //         wave owns k-octet. 8 float4 loads per tile.
  int colq;   // global col of storage row st = 4*lane (quad is contiguous)
  {
    const int st = 4 * lane;
    const int b  = st >> 7;
    const int r  = st & 127;
    const int w  = r >> 5;
    const int nf = (r >> 4) & 1;
    const int l4 = st & 15;
    if (SILU) colq = nb * 128 + (w * 32 + b * 16 + l4) + (nf ? I_ : 0);
    else      colq = nb * 256 + w * 64 + (b * 2 + nf) * 16 + l4;
  }
  const float* Bq = B + colq;

  f32x4 bv[8];
  auto LOADB = [&](int kt) {
    const long kbase = (long)kt * 64 + wave * 8;
#pragma unroll
    for (int i = 0; i < 8; ++i)
      bv[i] = *(const f32x4*)&Bq[(kbase + i) * (long)LDB];
  };
  auto WRITEB = [&](int bo) {
    char* LBw = smem + 65536 + bo * 32768;
    const int slot = wave ^ (lane & 7);           // (st>>2)&7 == lane&7
#pragma unroll
    for (int j = 0; j < 4; ++j) {
      bf16x8 pk;
#pragma unroll
      for (int i = 0; i < 8; ++i) pk[i] = (__bf16)bv[i][j];
      const int st = 4 * lane + j;
      *(bf16x8*)(LBw + st * 128 + slot * 16) = pk;
    }
  };

  // fragment-read swizzled slot offsets
  const int axA0 = ((0 + lq) ^ (lr & 7)) * 16;    // A: k 0..31
  const int axA1 = ((4 + lq) ^ (lr & 7)) * 16;    // A: k 32..63
  const int bxn[2] = { (lr >> 2), 4 + (lr >> 2) };  // B row-quad XOR per nf

  f32x4 acc[8][4];
#pragma unroll
  for (int m = 0; m < 8; ++m)
#pragma unroll
    for (int n = 0; n < 4; ++n) acc[m][n] = (f32x4)0.0f;

  // ---------------- prologue --------------------------------------------
  const int t1p = (NT > 1) ? 1 : 0;
  LOADB(0);                    // 8 f4  (B(0))
  stageA(0, 0, 0);             // 2 a16
  stageA(0, 1, 0);             // 2 a16
  SB0();
  WAITVM(4); SB0();            // B(0) done (leaves A(0) 4)
  WRITEB(0);
  WAITLGKM(); SB0();           // publish B(0); free bv (WAR)
  stageA(1, 0, t1p); SB0();    // 2  A(1)q0
  LOADB(t1p); SB0();           // 8  B(1)
  stageA(1, 1, t1p); SB0();    // 2  A(1)q1
  WAITVM(12); SB0();           // drain A(0); leaves [2,8,2]
  BAR();

#pragma unroll 1
  for (int t = 0; t < NT; ++t) {
    const int cur = t & 1;
    const int bo  = cur ^ 1;
    const char* LA = smem + cur * 32768;
    const char* LB = smem + 65536 + cur * 32768;
    const int t2v = (t + 2 < NT) ? t + 2 : NT - 1;

    bf16x8 a[4][2], b0[2][2], b1[2][2];

    // ---- P0: read a(q0)+b0; no VMEM ------------------------------------
#pragma unroll
    for (int mf = 0; mf < 4; ++mf) {
      const int st = wid_m * 64 + mf * 16 + lr;
      a[mf][0] = *(const bf16x8*)(LA + st * 128 + axA0);
      a[mf][1] = *(const bf16x8*)(LA + st * 128 + axA1);
    }
#pragma unroll
    for (int nf = 0; nf < 2; ++nf) {
      const int st = wid_n * 32 + nf * 16 + lr;
      b0[nf][0] = *(const bf16x8*)(LB + st * 128 + ((0 + lq) ^ bxn[nf]) * 16);
      b0[nf][1] = *(const bf16x8*)(LB + st * 128 + ((4 + lq) ^ bxn[nf]) * 16);
    }
    SB0();
    BAR();
    WAITLGKM(); SB0();
    __builtin_amdgcn_s_setprio(1);
#pragma unroll
    for (int mf = 0; mf < 4; ++mf)
#pragma unroll
      for (int nf = 0; nf < 2; ++nf) {
        acc[mf][nf] = __builtin_amdgcn_mfma_f32_16x16x32_bf16(a[mf][0], b0[nf][0], acc[mf][nf], 0, 0, 0);
        acc[mf][nf] = __builtin_amdgcn_mfma_f32_16x16x32_bf16(a[mf][1], b0[nf][1], acc[mf][nf], 0, 0, 0);
      }
    __builtin_amdgcn_s_setprio(0);
    BAR();

    // ---- P1: read b1; issue A(t+2)q0 -----------------------------------
#pragma unroll
    for (int nf = 0; nf < 2; ++nf) {
      const int st = 128 + wid_n * 32 + nf * 16 + lr;
      b1[nf][0] = *(const bf16x8*)(LB + st * 128 + ((0 + lq) ^ bxn[nf]) * 16);
      b1[nf][1] = *(const bf16x8*)(LB + st * 128 + ((4 + lq) ^ bxn[nf]) * 16);
    }
    stageA(cur, 0, t2v);
    SB0();
    BAR();
    WAITLGKM(); SB0();
    __builtin_amdgcn_s_setprio(1);
#pragma unroll
    for (int mf = 0; mf < 4; ++mf)
#pragma unroll
      for (int nf = 0; nf < 2; ++nf) {
        acc[mf][2 + nf] = __builtin_amdgcn_mfma_f32_16x16x32_bf16(a[mf][0], b1[nf][0], acc[mf][2 + nf], 0, 0, 0);
        acc[mf][2 + nf] = __builtin_amdgcn_mfma_f32_16x16x32_bf16(a[mf][1], b1[nf][1], acc[mf][2 + nf], 0, 0, 0);
      }
    __builtin_amdgcn_s_setprio(0);
    BAR();

    // ---- P2: read a(q1); vmcnt(4) -> write B(t+1); issue B(t+2) --------
#pragma unroll
    for (int mf = 0; mf < 4; ++mf) {
      const int st = 128 + wid_m * 64 + mf * 16 + lr;
      a[mf][0] = *(const bf16x8*)(LA + st * 128 + axA0);
      a[mf][1] = *(const bf16x8*)(LA + st * 128 + axA1);
    }
    SB0();
    WAITVM(4); SB0();          // B(t+1) regs ready (leaves Aq1(t+1), Aq0(t+2))
    WRITEB(bo);
    WAITLGKM(); SB0();         // drain a(q1) reads + B writes (WAR on bv)
    LOADB(t2v);                // 8 f4  B(t+2)
    SB0();
    BAR();
    __builtin_amdgcn_s_setprio(1);
#pragma unroll
    for (int mf = 0; mf < 4; ++mf)
#pragma unroll
      for (int nf = 0; nf < 2; ++nf) {
        acc[4 + mf][2 + nf] = __builtin_amdgcn_mfma_f32_16x16x32_bf16(a[mf][0], b1[nf][0], acc[4 + mf][2 + nf], 0, 0, 0);
        acc[4 + mf][2 + nf] = __builtin_amdgcn_mfma_f32_16x16x32_bf16(a[mf][1], b1[nf][1], acc[4 + mf][2 + nf], 0, 0, 0);
      }
    __builtin_amdgcn_s_setprio(0);
    BAR();

    // ---- P3: issue A(t+2)q1; vmcnt(12); MFMA on regs -------------------
    stageA(cur, 1, t2v);
    SB0();
    WAITVM(12); SB0();         // drain Aq1(t+1) (read next tile P2)
    BAR();
    __builtin_amdgcn_s_setprio(1);
#pragma unroll
    for (int mf = 0; mf < 4; ++mf)
#pragma unroll
      for (int nf = 0; nf < 2; ++nf) {
        acc[4 + mf][nf] = __builtin_amdgcn_mfma_f32_16x16x32_bf16(a[mf][0], b0[nf][0], acc[4 + mf][nf], 0, 0, 0);
        acc[4 + mf][nf] = __builtin_amdgcn_mfma_f32_16x16x32_bf16(a[mf][1], b0[nf][1], acc[4 + mf][nf], 0, 0, 0);
      }
    __builtin_amdgcn_s_setprio(0);
    BAR();
  }

  WAITVM(0);                   // trailing clamped loads must not outlive LDS

  // ---------------- epilogue (C/D: col=lane&15, row=(lane>>4)*4+r) -------
  if (SILU) {
    unsigned short* Cc = (unsigned short*)Cout + (long)e * sC;
#pragma unroll
    for (int mf = 0; mf < 8; ++mf)
#pragma unroll
      for (int p = 0; p < 2; ++p)
#pragma unroll
        for (int rr = 0; rr < 4; ++rr) {
          const int row = mb * 256 + wid_m * 128 + mf * 16 + lq * 4 + rr;
          const int col = nb * 128 + wid_n * 32 + p * 16 + lr;
          const float g = acc[mf][p * 2][rr];
          const float u = acc[mf][p * 2 + 1][rr];
          Cc[(long)row * I_ + col] = f2bf(u * (g / (1.0f + __expf(-g))));
        }
  } else {
    float* Cc = (float*)Cout + (long)e * sC;
#pragma unroll
    for (int mf = 0; mf < 8; ++mf)
#pragma unroll
      for (int q = 0; q < 4; ++q)
#pragma unroll
        for (int rr = 0; rr < 4; ++rr) {
          const int row = mb * 256 + wid_m * 128 + mf * 16 + lq * 4 + rr;
          const int col = nb * 256 + wid_n * 64 + q * 16 + lr;
          Cc[(long)row * H_ + col] = acc[mf][q][rr];
        }
  }
}

// ---------------------------------------------------------------------------
extern "C" void kernel_launch(void* const* d_in, const int* in_sizes, int n_in,
                              void* d_out, int out_size, void* d_ws, size_t ws_size,
                              hipStream_t stream) {
  const float* hs = (const float*)d_in[0];   // (8192, 2048)
  const float* w1 = (const float*)d_in[1];   // (8, 2048, 8192)
  const float* w2 = (const float*)d_in[2];   // (8, 4096, 2048)
  float* out = (float*)d_out;                // (8192, 2048) fp32
  char* ws = (char*)d_ws;

  const long HB_B  = (long)T_ * H_ * 2;      // 32 MiB hidden bf16
  const long ACT_B = (long)T_ * I_ * 2;      // 64 MiB acted bf16
  if (ws_size < (size_t)(HB_B + ACT_B)) return;

  unsigned short* hiddenB = (unsigned short*)(ws);
  unsigned short* acted   = (unsigned short*)(ws + HB_B);

  hipLaunchKernelGGL(convert_bf16, dim3(2048), dim3(256), 0, stream,
                     hs, hiddenB, (long)T_ * H_);

  // gemm1+SiLU: A=hiddenB (TPE,H), B=W1 (H,2I) fp32 direct -> acted bf16
  hipLaunchKernelGGL((gemm_fused<H_, 32, 2 * I_, true>),
                     dim3(1024), dim3(512), 131072, stream,
                     hiddenB, w1, acted,
                     (long)TPE * H_, (long)H_ * 2 * I_, (long)TPE * I_);

  // gemm2: A=acted (TPE,I), B=W2 (I,H) fp32 direct -> out fp32
  hipLaunchKernelGGL((gemm_fused<I_, 8, H_, false>),
                     dim3(256), dim3(512), 131072, stream,
                     acted, w2, out,
                     (long)TPE * I_, (long)I_ * H_, (long)TPE * H_);
}